// Round 7
// baseline (118.393 us; speedup 1.0000x reference)
//
#include <hip/hip_runtime.h>

// IoU3DLoss v7: frame-of-box1 geometry (axis-aligned box1: cheap in-box tests,
// 4 shared rcps for 16 crossings, constant crossing coords) + element-pair
// packed fp32 (v2f across the thread's 2 elements -> v_pk_* on CDNA4).
// Keeps: SoA slot-major LDS rank-scatter, packed-key Batcher-8 sort + gather.

typedef float v2f __attribute__((ext_vector_type(2)));
#define RCPF(x) __builtin_amdgcn_rcpf(x)

__device__ __forceinline__ v2f v2(float a, float b) { v2f r; r[0] = a; r[1] = b; return r; }
__device__ __forceinline__ v2f vabs(v2f a) { return v2(fabsf(a[0]), fabsf(a[1])); }

__device__ __forceinline__ unsigned sortKeyU(float f) {
    unsigned u = __float_as_uint(f);
    return (u & 0x80000000u) ? ~u : (u | 0x80000000u);   // monotone float->uint
}

// Batcher odd-even merge sort, 8 keys, 19 comparators (validated in v6)
__device__ __forceinline__ void sort8(unsigned k[8]) {
#define CE(a, b) { unsigned lo = min(k[a], k[b]); unsigned hi = max(k[a], k[b]); k[a] = lo; k[b] = hi; }
    CE(0,1) CE(2,3) CE(4,5) CE(6,7)
    CE(0,2) CE(1,3) CE(4,6) CE(5,7)
    CE(1,2) CE(5,6)
    CE(0,4) CE(1,5) CE(2,6) CE(3,7)
    CE(2,4) CE(3,5)
    CE(1,2) CE(3,4) CE(5,6)
#undef CE
}

// gather sorted coords from LDS by packed index, cyclic shoelace over kcnt
__device__ __forceinline__ float shoelace8(const float* __restrict__ Xb,
                                           const float* __restrict__ Yb,
                                           const unsigned* __restrict__ key, int kcnt) {
    float sx[8], sy[8];
    #pragma unroll
    for (int j = 0; j < 8; ++j) {
        unsigned idx = key[j] & 7u;
        sx[j] = Xb[idx * 256];
        sy[j] = Yb[idx * 256];
    }
    float x0 = sx[0], y0 = sy[0], area2 = 0.0f;
    #pragma unroll
    for (int v = 0; v < 8; ++v) {
        bool act = (v < kcnt);
        bool wrap = (v + 1 == kcnt);
        float nx2 = (v == 7) ? x0 : (wrap ? x0 : sx[v + 1]);
        float ny2 = (v == 7) ? y0 : (wrap ? y0 : sy[v + 1]);
        float term = sx[v] * ny2 - nx2 * sy[v];
        area2 += act ? term : 0.0f;
    }
    return area2;
}

__global__ __launch_bounds__(256, 4) void iou3d_loss_kernel(
    const float* __restrict__ pred_iou,
    const float* __restrict__ pred_boxes,
    const float* __restrict__ gt_boxes,
    const int*   __restrict__ mask,
    float* __restrict__ sums,
    int M)
{
    __shared__ float sXs[2][9][256];
    __shared__ float sYs[2][9][256];
    const int tid = threadIdx.x;
    float* __restrict__ Xb0 = &sXs[0][0][tid];
    float* __restrict__ Yb0 = &sYs[0][0][tid];
    float* __restrict__ Xb1 = &sXs[1][0][tid];
    float* __restrict__ Yb1 = &sYs[1][0][tid];

    const int idx0 = blockIdx.x * blockDim.x + tid;
    const int stride = gridDim.x * blockDim.x;
    const int idx1 = idx0 + stride;
    const int ml = M - 1;
    const int i0 = idx0 < M ? idx0 : ml;
    const int i1 = idx1 < M ? idx1 : ml;

    // ---- loads, packed across the element pair ----
    const float* pbA = pred_boxes + (size_t)i0 * 7;
    const float* pbB = pred_boxes + (size_t)i1 * 7;
    v2f bx = v2(pbA[0], pbB[0]);
    v2f by = v2(pbA[1], pbB[1]);
    v2f bz = v2(pbA[2], pbB[2]);
    v2f w1 = v2(pbA[3], pbB[3]);
    v2f h1 = v2(pbA[4], pbB[4]);
    v2f l1 = v2(pbA[5], pbB[5]);
    const float a1A = pbA[6], a1B = pbB[6];

    const float4 gA0 = reinterpret_cast<const float4*>(gt_boxes)[(size_t)i0 * 2 + 0];
    const float4 gA1 = reinterpret_cast<const float4*>(gt_boxes)[(size_t)i0 * 2 + 1];
    const float4 gB0 = reinterpret_cast<const float4*>(gt_boxes)[(size_t)i1 * 2 + 0];
    const float4 gB1 = reinterpret_cast<const float4*>(gt_boxes)[(size_t)i1 * 2 + 1];
    v2f gx = v2(gA0.x, gB0.x), gy = v2(gA0.y, gB0.y), gz = v2(gA0.z, gB0.z);
    v2f w2 = v2(gA0.w, gB0.w), h2 = v2(gA1.x, gB1.x), l2 = v2(gA1.y, gB1.y);
    v2f gsn = v2(gA1.z, gB1.z), gcs = v2(gA1.w, gB1.w);

    const float predA = pred_iou[i0], predB = pred_iou[i1];
    const float mfA = (idx0 < M && mask[i0] != 0) ? 1.0f : 0.0f;
    const float mfB = (idx1 < M && mask[i1] != 0) ? 1.0f : 0.0f;

    // ---- trig / relative rotation ----
    float snA, csA, snB, csB;
    __sincosf(a1A, &snA, &csA);
    __sincosf(a1B, &snB, &csB);
    v2f sn1 = v2(snA, snB), cs1 = v2(csA, csB);
    v2f rn = v2(__builtin_amdgcn_rsqf(gsn[0]*gsn[0] + gcs[0]*gcs[0]),
                __builtin_amdgcn_rsqf(gsn[1]*gsn[1] + gcs[1]*gcs[1]));
    v2f sn2 = gsn * rn, cs2 = gcs * rn;
    v2f cs21 = cs2 * cs1 + sn2 * sn1;   // cos(a2-a1)
    v2f sn21 = sn2 * cs1 - cs2 * sn1;   // sin(a2-a1)

    v2f hw1 = 0.5f * w1, hh1 = 0.5f * h1, hw2 = 0.5f * w2, hh2 = 0.5f * h2;
    v2f nhw1 = -hw1, nhh1 = -hh1;

    // box2 center in frame1: d1 = R(-a1)*(C2-C1)
    v2f cdx = gx - bx, cdy = gy - by;
    v2f d1x = cdx * cs1 + cdy * sn1;
    v2f d1y = cdy * cs1 - cdx * sn1;

    // box2 corners in frame1: B_k = d1 + R21*(sx*hw2, sy*hh2)
    v2f ru = hw2 * cs21, rv = hh2 * sn21, rp = hw2 * sn21, rq = hh2 * cs21;
    v2f Bx[4], By[4];
    Bx[0] = d1x + ru - rv;  By[0] = d1y + rp + rq;   // (+,+)
    Bx[1] = d1x - ru - rv;  By[1] = d1y - rp + rq;   // (-,+)
    Bx[2] = d1x - ru + rv;  By[2] = d1y - rp - rq;   // (-,-)
    Bx[3] = d1x + ru + rv;  By[3] = d1y + rp - rq;   // (+,-)

    // box2 edge vectors in frame1 (m=0: B0-B1; m=1: B1-B2; m=2/3 = negated)
    v2f e2x0 = w2 * cs21, e2y0 = w2 * sn21;
    v2f e2x1 = -(h2 * sn21), e2y1 = h2 * cs21;
    v2f ae2x0 = vabs(e2x0), ae2y0 = vabs(e2y0);
    v2f ae2x1 = vabs(e2x1), ae2y1 = vabs(e2y1);
    // den magnitudes & shared reciprocals (4 distinct rcps per element)
    v2f P0 = w1 * e2y0, P1 = w1 * e2y1, Q0 = h1 * e2x0, Q1 = h1 * e2x1;
    v2f aP0 = vabs(P0), aP1 = vabs(P1), aQ0 = vabs(Q0), aQ1 = vabs(Q1);
    v2f rP0 = v2(RCPF(P0[0]), RCPF(P0[1])), rP1 = v2(RCPF(P1[0]), RCPF(P1[1]));
    v2f rQ0 = v2(RCPF(Q0[0]), RCPF(Q0[1])), rQ1 = v2(RCPF(Q1[0]), RCPF(Q1[1]));

    const float eps = 1e-6f;
    v2f tx1 = hw1 + eps * w1, ty1 = hh1 + eps * h1;   // |p|<thr == ref's pab/pad test
    v2f tx2 = hw2 + eps * w2, ty2 = hh2 + eps * h2;

    // ---- streaming rank-scatter (same proven semantics as v4/v6) ----
    unsigned rr0 = 0u, rr1 = 0u;
#define EMIT0(xv, yv, ok) { unsigned rm = rr0 < 8u ? rr0 : 8u; Xb0[rm*256] = (xv); Yb0[rm*256] = (yv); rr0 += (ok) ? 1u : 0u; }
#define EMIT1(xv, yv, ok) { unsigned rm = rr1 < 8u ? rr1 : 8u; Xb1[rm*256] = (xv); Yb1[rm*256] = (yv); rr1 += (ok) ? 1u : 0u; }

    {   // candidates 0-3: box1 corners (frame1 = (+-hw1,+-hh1)), valid iff in box2
        v2f uxp = hw1 - d1x, uxm = nhw1 - d1x;
        v2f uyp = hh1 - d1y, uym = nhh1 - d1y;
        #pragma unroll
        for (int k = 0; k < 4; ++k) {
            v2f ux = (k == 0 || k == 3) ? uxp : uxm;
            v2f uy = (k < 2) ? uyp : uym;
            v2f ax2 = ux * cs21 + uy * sn21;      // corner in frame2
            v2f ay2 = uy * cs21 - ux * sn21;
            v2f Axv = (k == 0 || k == 3) ? hw1 : nhw1;
            v2f Ayv = (k < 2) ? hh1 : nhh1;
            bool o0 = fabsf(ax2[0]) < tx2[0] && fabsf(ay2[0]) < ty2[0];
            bool o1 = fabsf(ax2[1]) < tx2[1] && fabsf(ay2[1]) < ty2[1];
            EMIT0(Axv[0], Ayv[0], o0)
            EMIT1(Axv[1], Ayv[1], o1)
        }
    }
    {   // candidates 4-7: box2 corners (frame1), valid iff |Bx|<tx1 && |By|<ty1
        #pragma unroll
        for (int k = 0; k < 4; ++k) {
            bool o0 = fabsf(Bx[k][0]) < tx1[0] && fabsf(By[k][0]) < ty1[0];
            bool o1 = fabsf(Bx[k][1]) < tx1[1] && fabsf(By[k][1]) < ty1[1];
            EMIT0(Bx[k][0], By[k][0], o0)
            EMIT1(Bx[k][1], By[k][1], o1)
        }
    }
    // candidates 8-23: crossings, reference's phantom t/u semantics, derived
    // symbolically from the bit-verified v6 formulas with e1 axis-aligned.
    // l=0: p1=(hw1,hh1), t-ok sign +.  l=2: p1=(-hw1,-hh1), sign -.
    #pragma unroll
    for (int m = 0; m < 4; ++m) {               // l = 0
        const bool bb = m & 1, mp = m < 2;
        v2f e2xb = bb ? e2x1 : e2x0, e2yb = bb ? e2y1 : e2y0;
        v2f aeyb = bb ? ae2y1 : ae2y0;
        v2f Pb = bb ? P1 : P0, aPb = bb ? aP1 : aP0, rPb = bb ? rP1 : rP0;
        v2f rx = hw1 - Bx[m], ry = hh1 - By[m];
        v2f nt = e2xb * ry - e2yb * rx;
        v2f q1 = nt * Pb, q2 = ry * e2yb;
        v2f Xv = hw1 - (nt * rPb) * w1;
        bool o0 = (q1[0] > 0.0f) && (fabsf(nt[0]) < aPb[0]) &&
                  (mp ? q2[0] > 0.0f : q2[0] < 0.0f) && (fabsf(ry[0]) < aeyb[0]);
        bool o1 = (q1[1] > 0.0f) && (fabsf(nt[1]) < aPb[1]) &&
                  (mp ? q2[1] > 0.0f : q2[1] < 0.0f) && (fabsf(ry[1]) < aeyb[1]);
        EMIT0(Xv[0], hh1[0], o0)
        EMIT1(Xv[1], hh1[1], o1)
    }
    #pragma unroll
    for (int m = 0; m < 4; ++m) {               // l = 1: p1=(-hw1,hh1), sign -
        const bool bb = m & 1, mp = m < 2;
        v2f e2xb = bb ? e2x1 : e2x0, e2yb = bb ? e2y1 : e2y0;
        v2f aexb = bb ? ae2x1 : ae2x0;
        v2f Qb = bb ? Q1 : Q0, aQb = bb ? aQ1 : aQ0, rQb = bb ? rQ1 : rQ0;
        v2f rx = nhw1 - Bx[m], ry = hh1 - By[m];
        v2f nt = e2xb * ry - e2yb * rx;
        v2f q1 = nt * Qb, q2 = rx * e2xb;
        v2f Yv = hh1 + (nt * rQb) * h1;
        bool o0 = (q1[0] < 0.0f) && (fabsf(nt[0]) < aQb[0]) &&
                  (mp ? q2[0] > 0.0f : q2[0] < 0.0f) && (fabsf(rx[0]) < aexb[0]);
        bool o1 = (q1[1] < 0.0f) && (fabsf(nt[1]) < aQb[1]) &&
                  (mp ? q2[1] > 0.0f : q2[1] < 0.0f) && (fabsf(rx[1]) < aexb[1]);
        EMIT0(nhw1[0], Yv[0], o0)
        EMIT1(nhw1[1], Yv[1], o1)
    }
    #pragma unroll
    for (int m = 0; m < 4; ++m) {               // l = 2: p1=(-hw1,-hh1), sign -
        const bool bb = m & 1, mp = m < 2;
        v2f e2xb = bb ? e2x1 : e2x0, e2yb = bb ? e2y1 : e2y0;
        v2f aeyb = bb ? ae2y1 : ae2y0;
        v2f Pb = bb ? P1 : P0, aPb = bb ? aP1 : aP0, rPb = bb ? rP1 : rP0;
        v2f rx = nhw1 - Bx[m], ry = nhh1 - By[m];
        v2f nt = e2xb * ry - e2yb * rx;
        v2f q1 = nt * Pb, q2 = ry * e2yb;
        v2f Xv = nhw1 - (nt * rPb) * w1;
        bool o0 = (q1[0] < 0.0f) && (fabsf(nt[0]) < aPb[0]) &&
                  (mp ? q2[0] > 0.0f : q2[0] < 0.0f) && (fabsf(ry[0]) < aeyb[0]);
        bool o1 = (q1[1] < 0.0f) && (fabsf(nt[1]) < aPb[1]) &&
                  (mp ? q2[1] > 0.0f : q2[1] < 0.0f) && (fabsf(ry[1]) < aeyb[1]);
        EMIT0(Xv[0], nhh1[0], o0)
        EMIT1(Xv[1], nhh1[1], o1)
    }
    #pragma unroll
    for (int m = 0; m < 4; ++m) {               // l = 3: p1=(hw1,-hh1), sign +
        const bool bb = m & 1, mp = m < 2;
        v2f e2xb = bb ? e2x1 : e2x0, e2yb = bb ? e2y1 : e2y0;
        v2f aexb = bb ? ae2x1 : ae2x0;
        v2f Qb = bb ? Q1 : Q0, aQb = bb ? aQ1 : aQ0, rQb = bb ? rQ1 : rQ0;
        v2f rx = hw1 - Bx[m], ry = nhh1 - By[m];
        v2f nt = e2xb * ry - e2yb * rx;
        v2f q1 = nt * Qb, q2 = rx * e2xb;
        v2f Yv = nhh1 + (nt * rQb) * h1;
        bool o0 = (q1[0] > 0.0f) && (fabsf(nt[0]) < aQb[0]) &&
                  (mp ? q2[0] > 0.0f : q2[0] < 0.0f) && (fabsf(rx[0]) < aexb[0]);
        bool o1 = (q1[1] > 0.0f) && (fabsf(nt[1]) < aQb[1]) &&
                  (mp ? q2[1] > 0.0f : q2[1] < 0.0f) && (fabsf(rx[1]) < aexb[1]);
        EMIT0(hw1[0], Yv[0], o0)
        EMIT1(hw1[1], Yv[1], o1)
    }
#undef EMIT0
#undef EMIT1

    // ---- readback + centroid ----
    v2f pxv[8], pyv[8];
    #pragma unroll
    for (int j = 0; j < 8; ++j) {
        pxv[j] = v2(Xb0[j * 256], Xb1[j * 256]);
        pyv[j] = v2(Yb0[j * 256], Yb1[j * 256]);
    }
    const int kc0 = (int)(rr0 < 8u ? rr0 : 8u);
    const int kc1 = (int)(rr1 < 8u ? rr1 : 8u);
    float sx0 = 0.f, sy0 = 0.f, sx1 = 0.f, sy1 = 0.f;
    #pragma unroll
    for (int j = 0; j < 8; ++j) {
        sx0 += (j < kc0) ? pxv[j][0] : 0.0f;
        sy0 += (j < kc0) ? pyv[j][0] : 0.0f;
        sx1 += (j < kc1) ? pxv[j][1] : 0.0f;
        sy1 += (j < kc1) ? pyv[j][1] : 0.0f;
    }
    const float rnv0 = RCPF(fmaxf((float)kc0, 1.0f));
    const float rnv1 = RCPF(fmaxf((float)kc1, 1.0f));
    v2f mxv = v2(sx0 * rnv0, sx1 * rnv1);
    v2f myv = v2(sy0 * rnv0, sy1 * rnv1);

    // ---- packed pseudo-angle keys ----
    unsigned k0[8], k1[8];
    #pragma unroll
    for (int j = 0; j < 8; ++j) {
        v2f dxx = pxv[j] - mxv, dyy = pyv[j] - myv;
        float ad0 = fabsf(dxx[0]) + fabsf(dyy[0]);
        float ad1 = fabsf(dxx[1]) + fabsf(dyy[1]);
        float r0 = dxx[0] * RCPF(fmaxf(ad0, 1e-30f));
        float r1 = dxx[1] * RCPF(fmaxf(ad1, 1e-30f));
        float kf0 = __builtin_copysignf(1.0f - r0, dyy[0]);
        float kf1 = __builtin_copysignf(1.0f - r1, dyy[1]);
        kf0 = (j < kc0) ? kf0 : 1e9f;
        kf1 = (j < kc1) ? kf1 : 1e9f;
        k0[j] = (sortKeyU(kf0) & 0xFFFFFFF8u) | (unsigned)j;
        k1[j] = (sortKeyU(kf1) & 0xFFFFFFF8u) | (unsigned)j;
    }
    sort8(k0);
    sort8(k1);
    const float area0 = shoelace8(Xb0, Yb0, k0, kc0);
    const float area1 = shoelace8(Xb1, Yb1, k1, kc1);
    v2f inter2d = 0.5f * v2(fabsf(area0), fabsf(area1));

    // ---- z overlap + volumes + iou ----
    v2f zmax1 = bz + 0.5f * l1, zmin1 = bz - 0.5f * l1;
    v2f zmax2 = gz + 0.5f * l2, zmin2 = gz - 0.5f * l2;
    v2f zov = v2(fmaxf(fminf(zmax1[0], zmax2[0]) - fmaxf(zmin1[0], zmin2[0]), 0.0f),
                 fmaxf(fminf(zmax1[1], zmax2[1]) - fmaxf(zmin1[1], zmin2[1]), 0.0f));
    v2f inter3d = inter2d * zov;
    v2f vol1 = w1 * h1 * l1, vol2 = w2 * h2 * l2;
    v2f uni = vol1 + vol2 - inter3d;
    v2f iou = inter3d * v2(RCPF(uni[0]), RCPF(uni[1]));

    // ---- diou extras (world corners 0/2 recomputed directly) ----
    v2f idg = (bx - gx) * (bx - gx) + (by - gy) * (by - gy) + (bz - gz) * (bz - gz);
    v2f v1x = hw1 * cs1 - hh1 * sn1, v1y = hw1 * sn1 + hh1 * cs1;
    v2f w2x = hw2 * cs2 - hh2 * sn2, w2y = hw2 * sn2 + hh2 * cs2;
    float oh0 = fmaxf(fmaxf(zmax1[0], zmax2[0]) - fminf(zmin1[0], zmin2[0]), 0.0f);
    float oh1 = fmaxf(fmaxf(zmax1[1], zmax2[1]) - fminf(zmin1[1], zmin2[1]), 0.0f);
    float omx0 = fmaxf(fmaxf(bx[0]-v1x[0], gx[0]-w2x[0]) - fminf(bx[0]+v1x[0], gx[0]+w2x[0]), 0.0f);
    float omy0 = fmaxf(fmaxf(by[0]-v1y[0], gy[0]-w2y[0]) - fminf(by[0]+v1y[0], gy[0]+w2y[0]), 0.0f);
    float omx1 = fmaxf(fmaxf(bx[1]-v1x[1], gx[1]-w2x[1]) - fminf(bx[1]+v1x[1], gx[1]+w2x[1]), 0.0f);
    float omy1 = fmaxf(fmaxf(by[1]-v1y[1], gy[1]-w2y[1]) - fminf(by[1]+v1y[1], gy[1]+w2y[1]), 0.0f);
    float od0 = omx0 * omx0 + omy0 * omy0 + oh0 * oh0;
    float od1 = omx1 * omx1 + omy1 * omy1 + oh1 * oh1;
    float diou0 = fminf(fmaxf(iou[0] - idg[0] * RCPF(od0), -1.0f), 1.0f);
    float diou1 = fminf(fmaxf(iou[1] - idg[1] * RCPF(od1), -1.0f), 1.0f);

    float t0 = iou[0] * 2.0f - 1.0f, t1 = iou[1] * 2.0f - 1.0f;
    float contrib = (fabsf(predA - t0) + (1.0f - diou0)) * mfA
                  + (fabsf(predB - t1) + (1.0f - diou1)) * mfB;
    float mfv = mfA + mfB;

    // ---- block reduction: wave shuffle -> LDS -> one atomic pair ----
    #pragma unroll
    for (int off = 32; off > 0; off >>= 1) {
        contrib += __shfl_down(contrib, off, 64);
        mfv     += __shfl_down(mfv, off, 64);
    }
    __shared__ float sC[4], sM[4];
    const int lane = tid & 63;
    const int wv = tid >> 6;
    if (lane == 0) { sC[wv] = contrib; sM[wv] = mfv; }
    __syncthreads();
    if (tid == 0) {
        float tc = sC[0] + sC[1] + sC[2] + sC[3];
        float tm = sM[0] + sM[1] + sM[2] + sM[3];
        atomicAdd(&sums[0], tc);
        atomicAdd(&sums[1], tm);
    }
}

__global__ void finalize_kernel(const float* __restrict__ sums, float* __restrict__ out) {
    if (threadIdx.x == 0 && blockIdx.x == 0)
        out[0] = sums[0] / fmaxf(sums[1], 1e-4f);
}

extern "C" void kernel_launch(void* const* d_in, const int* in_sizes, int n_in,
                              void* d_out, int out_size, void* d_ws, size_t ws_size,
                              hipStream_t stream) {
    const float* pred_iou   = (const float*)d_in[0];
    const float* pred_boxes = (const float*)d_in[1];
    const float* gt_boxes   = (const float*)d_in[2];
    const int*   mask       = (const int*)d_in[3];
    float* out  = (float*)d_out;
    float* sums = (float*)d_ws;
    const int M = in_sizes[0];

    hipMemsetAsync(sums, 0, 2 * sizeof(float), stream);
    const int block = 256;
    const int elems_per_thread = 2;
    int grid = (M + block * elems_per_thread - 1) / (block * elems_per_thread);
    if (grid < 1) grid = 1;
    hipLaunchKernelGGL(iou3d_loss_kernel, dim3(grid), dim3(block), 0, stream,
                       pred_iou, pred_boxes, gt_boxes, mask, sums, M);
    hipLaunchKernelGGL(finalize_kernel, dim3(1), dim3(64), 0, stream, sums, out);
}

// Round 8
// 111.955 us; speedup vs baseline: 1.0575x; 1.0575x over previous
//
#include <hip/hip_runtime.h>

// IoU3DLoss v8: frame-of-box1 geometry (verified bit-exact in v7) in plain
// SCALAR form (v7's v2f packing was the regression: lane extracts + VOP3P
// regalloc ate the savings). Config = v4/v6 best: 2 elems/thread via two
// elem_body calls, SoA slot-major LDS rank-scatter, packed-key Batcher sort.

#define RCPF(x) __builtin_amdgcn_rcpf(x)

__device__ __forceinline__ unsigned sortKeyU(float f) {
    unsigned u = __float_as_uint(f);
    return (u & 0x80000000u) ? ~u : (u | 0x80000000u);   // monotone float->uint
}

// Batcher odd-even merge sort, 8 keys, 19 comparators (validated v6/v7)
__device__ __forceinline__ void sort8(unsigned k[8]) {
#define CE(a, b) { unsigned lo = min(k[a], k[b]); unsigned hi = max(k[a], k[b]); k[a] = lo; k[b] = hi; }
    CE(0,1) CE(2,3) CE(4,5) CE(6,7)
    CE(0,2) CE(1,3) CE(4,6) CE(5,7)
    CE(1,2) CE(5,6)
    CE(0,4) CE(1,5) CE(2,6) CE(3,7)
    CE(2,4) CE(3,5)
    CE(1,2) CE(3,4) CE(5,6)
#undef CE
}

struct EIn {
    float b[7];   // pred box: x,y,z,w,h,l,alpha
    float g[8];   // gt box:   x,y,z,w,h,l,sin,cos
    float pred;
    float mf;
};

__device__ __forceinline__ void load_elem(EIn& e,
    const float* __restrict__ pred_iou, const float* __restrict__ pred_boxes,
    const float* __restrict__ gt_boxes, const int* __restrict__ mask,
    int gid, bool active)
{
    const float* pb = pred_boxes + (size_t)gid * 7;
    #pragma unroll
    for (int k = 0; k < 7; ++k) e.b[k] = pb[k];
    const float4 g0 = reinterpret_cast<const float4*>(gt_boxes)[(size_t)gid * 2 + 0];
    const float4 g1 = reinterpret_cast<const float4*>(gt_boxes)[(size_t)gid * 2 + 1];
    e.g[0] = g0.x; e.g[1] = g0.y; e.g[2] = g0.z; e.g[3] = g0.w;
    e.g[4] = g1.x; e.g[5] = g1.y; e.g[6] = g1.z; e.g[7] = g1.w;
    e.pred = pred_iou[gid];
    e.mf = (active && mask[gid] != 0) ? 1.0f : 0.0f;
}

// X, Y: this thread's LDS bases; slot j lives at X[j*256], Y[j*256].
__device__ __forceinline__ float elem_body(const EIn& e,
    float* __restrict__ X, float* __restrict__ Y)
{
    const float bx = e.b[0], by = e.b[1], bz = e.b[2];
    const float w1 = e.b[3], h1 = e.b[4], l1 = e.b[5], a1 = e.b[6];
    const float gx = e.g[0], gy = e.g[1], gz = e.g[2];
    const float w2 = e.g[3], h2 = e.g[4], l2 = e.g[5];
    const float gsn = e.g[6], gcs = e.g[7];

    float sn1, cs1;
    __sincosf(a1, &sn1, &cs1);
    const float rn = __builtin_amdgcn_rsqf(gsn * gsn + gcs * gcs);
    const float sn2 = gsn * rn, cs2 = gcs * rn;
    const float cs21 = cs2 * cs1 + sn2 * sn1;   // cos(a2-a1)
    const float sn21 = sn2 * cs1 - cs2 * sn1;   // sin(a2-a1)

    const float hw1 = 0.5f * w1, hh1 = 0.5f * h1;
    const float hw2 = 0.5f * w2, hh2 = 0.5f * h2;
    const float nhw1 = -hw1, nhh1 = -hh1;

    // box2 center in frame1
    const float cdx = gx - bx, cdy = gy - by;
    const float d1x = cdx * cs1 + cdy * sn1;
    const float d1y = cdy * cs1 - cdx * sn1;

    // box2 corners in frame1 (order (+,+),(-,+),(-,-),(+,-) = reference's)
    const float ru = hw2 * cs21, rv = hh2 * sn21;
    const float rp = hw2 * sn21, rq = hh2 * cs21;
    float Bx[4], By[4];
    Bx[0] = d1x + ru - rv;  By[0] = d1y + rp + rq;
    Bx[1] = d1x - ru - rv;  By[1] = d1y - rp + rq;
    Bx[2] = d1x - ru + rv;  By[2] = d1y - rp - rq;
    Bx[3] = d1x + ru + rv;  By[3] = d1y + rp - rq;

    // box2 edge vectors in frame1 (m=0: B0-B1; m=1: B1-B2; m=2/3 negated —
    // sign bookkeeping folded into the q-tests, bit-verified in v7)
    const float e2x0 = w2 * cs21,    e2y0 = w2 * sn21;
    const float e2x1 = -(h2 * sn21), e2y1 = h2 * cs21;
    const float ae2x0 = fabsf(e2x0), ae2y0 = fabsf(e2y0);
    const float ae2x1 = fabsf(e2x1), ae2y1 = fabsf(e2y1);
    // shared denominators: only 4 distinct rcps for all 16 crossings
    const float P0 = w1 * e2y0, P1 = w1 * e2y1;
    const float Q0 = h1 * e2x0, Q1 = h1 * e2x1;
    const float aP0 = fabsf(P0), aP1 = fabsf(P1);
    const float aQ0 = fabsf(Q0), aQ1 = fabsf(Q1);
    const float rP0 = RCPF(P0), rP1 = RCPF(P1);
    const float rQ0 = RCPF(Q0), rQ1 = RCPF(Q1);

    const float eps = 1e-6f;
    const float tx1 = hw1 + eps * w1, ty1 = hh1 + eps * h1;
    const float tx2 = hw2 + eps * w2, ty2 = hh2 + eps * h2;

    // ---- streaming rank-scatter (proven v4/v6 semantics) ----
    unsigned r = 0u;
#define EMIT(xv, yv, ok) { unsigned rm = r < 8u ? r : 8u; \
                           X[rm * 256] = (xv); Y[rm * 256] = (yv); \
                           r += (ok) ? 1u : 0u; }

    {   // candidates 0-3: box1 corners (axis-aligned in frame1), in-box2 test
        const float uxp = hw1 - d1x, uxm = nhw1 - d1x;
        const float uyp = hh1 - d1y, uym = nhh1 - d1y;
        #pragma unroll
        for (int k = 0; k < 4; ++k) {
            const float ux = (k == 0 || k == 3) ? uxp : uxm;
            const float uy = (k < 2) ? uyp : uym;
            const float ax2 = ux * cs21 + uy * sn21;   // corner in frame2
            const float ay2 = uy * cs21 - ux * sn21;
            const float Axv = (k == 0 || k == 3) ? hw1 : nhw1;
            const float Ayv = (k < 2) ? hh1 : nhh1;
            const bool ok = fabsf(ax2) < tx2 && fabsf(ay2) < ty2;
            EMIT(Axv, Ayv, ok)
        }
    }
    {   // candidates 4-7: box2 corners, in-box1 test is 2 abs-compares
        #pragma unroll
        for (int k = 0; k < 4; ++k) {
            const bool ok = fabsf(Bx[k]) < tx1 && fabsf(By[k]) < ty1;
            EMIT(Bx[k], By[k], ok)
        }
    }
    // candidates 8-23: crossings (reference's phantom t/u semantics,
    // frame-form bit-verified in v7: absmax 0.0 over 524K random elems)
    #pragma unroll
    for (int m = 0; m < 4; ++m) {               // l = 0: p1=(hw1,hh1)
        const bool bb = m & 1; const bool mp = m < 2;
        const float e2xb = bb ? e2x1 : e2x0, e2yb = bb ? e2y1 : e2y0;
        const float aeyb = bb ? ae2y1 : ae2y0;
        const float Pb = bb ? P1 : P0, aPb = bb ? aP1 : aP0, rPb = bb ? rP1 : rP0;
        const float rx = hw1 - Bx[m], ry = hh1 - By[m];
        const float nt = e2xb * ry - e2yb * rx;
        const float q1 = nt * Pb, q2 = ry * e2yb;
        const float Xv = hw1 - (nt * rPb) * w1;
        const bool ok = (q1 > 0.0f) && (fabsf(nt) < aPb) &&
                        (mp ? q2 > 0.0f : q2 < 0.0f) && (fabsf(ry) < aeyb);
        EMIT(Xv, hh1, ok)
    }
    #pragma unroll
    for (int m = 0; m < 4; ++m) {               // l = 1: p1=(-hw1,hh1)
        const bool bb = m & 1; const bool mp = m < 2;
        const float e2xb = bb ? e2x1 : e2x0, e2yb = bb ? e2y1 : e2y0;
        const float aexb = bb ? ae2x1 : ae2x0;
        const float Qb = bb ? Q1 : Q0, aQb = bb ? aQ1 : aQ0, rQb = bb ? rQ1 : rQ0;
        const float rx = nhw1 - Bx[m], ry = hh1 - By[m];
        const float nt = e2xb * ry - e2yb * rx;
        const float q1 = nt * Qb, q2 = rx * e2xb;
        const float Yv = hh1 + (nt * rQb) * h1;
        const bool ok = (q1 < 0.0f) && (fabsf(nt) < aQb) &&
                        (mp ? q2 > 0.0f : q2 < 0.0f) && (fabsf(rx) < aexb);
        EMIT(nhw1, Yv, ok)
    }
    #pragma unroll
    for (int m = 0; m < 4; ++m) {               // l = 2: p1=(-hw1,-hh1)
        const bool bb = m & 1; const bool mp = m < 2;
        const float e2xb = bb ? e2x1 : e2x0, e2yb = bb ? e2y1 : e2y0;
        const float aeyb = bb ? ae2y1 : ae2y0;
        const float Pb = bb ? P1 : P0, aPb = bb ? aP1 : aP0, rPb = bb ? rP1 : rP0;
        const float rx = nhw1 - Bx[m], ry = nhh1 - By[m];
        const float nt = e2xb * ry - e2yb * rx;
        const float q1 = nt * Pb, q2 = ry * e2yb;
        const float Xv = nhw1 - (nt * rPb) * w1;
        const bool ok = (q1 < 0.0f) && (fabsf(nt) < aPb) &&
                        (mp ? q2 > 0.0f : q2 < 0.0f) && (fabsf(ry) < aeyb);
        EMIT(Xv, nhh1, ok)
    }
    #pragma unroll
    for (int m = 0; m < 4; ++m) {               // l = 3: p1=(hw1,-hh1)
        const bool bb = m & 1; const bool mp = m < 2;
        const float e2xb = bb ? e2x1 : e2x0, e2yb = bb ? e2y1 : e2y0;
        const float aexb = bb ? ae2x1 : ae2x0;
        const float Qb = bb ? Q1 : Q0, aQb = bb ? aQ1 : aQ0, rQb = bb ? rQ1 : rQ0;
        const float rx = hw1 - Bx[m], ry = nhh1 - By[m];
        const float nt = e2xb * ry - e2yb * rx;
        const float q1 = nt * Qb, q2 = rx * e2xb;
        const float Yv = nhh1 + (nt * rQb) * h1;
        const bool ok = (q1 > 0.0f) && (fabsf(nt) < aQb) &&
                        (mp ? q2 > 0.0f : q2 < 0.0f) && (fabsf(rx) < aexb);
        EMIT(hw1, Yv, ok)
    }
#undef EMIT

    // ---- readback + centroid ----
    float px[8], py[8];
    #pragma unroll
    for (int j = 0; j < 8; ++j) {
        px[j] = X[j * 256];
        py[j] = Y[j * 256];
    }
    const int kcnt = (int)(r < 8u ? r : 8u);
    float sxm = 0.0f, sym = 0.0f;
    #pragma unroll
    for (int j = 0; j < 8; ++j) {
        const bool a = (j < kcnt);
        sxm += a ? px[j] : 0.0f;
        sym += a ? py[j] : 0.0f;
    }
    const float rnv = RCPF(fmaxf((float)kcnt, 1.0f));
    const float mx = sxm * rnv, my = sym * rnv;

    // packed pseudo-angle keys (diamond angle == atan2 cyclic order)
    unsigned key[8];
    #pragma unroll
    for (int j = 0; j < 8; ++j) {
        const float dx = px[j] - mx, dy = py[j] - my;
        const float ad = fabsf(dx) + fabsf(dy);
        const float rr = dx * RCPF(fmaxf(ad, 1e-30f));
        float kf = __builtin_copysignf(1.0f - rr, dy);
        kf = (j < kcnt) ? kf : 1e9f;
        key[j] = (sortKeyU(kf) & 0xFFFFFFF8u) | (unsigned)j;
    }
    sort8(key);

    // gather sorted coords from LDS, cyclic shoelace over first kcnt
    float sx[8], sy[8];
    #pragma unroll
    for (int j = 0; j < 8; ++j) {
        const unsigned idx = key[j] & 7u;
        sx[j] = X[idx * 256];
        sy[j] = Y[idx * 256];
    }
    const float x0 = sx[0], y0 = sy[0];
    float area2 = 0.0f;
    #pragma unroll
    for (int v = 0; v < 8; ++v) {
        const bool act = (v < kcnt);
        const bool wrap = (v + 1 == kcnt);
        const float nx2 = (v == 7) ? x0 : (wrap ? x0 : sx[v + 1]);
        const float ny2 = (v == 7) ? y0 : (wrap ? y0 : sy[v + 1]);
        const float term = sx[v] * ny2 - nx2 * sy[v];
        area2 += act ? term : 0.0f;
    }
    const float inter2d = 0.5f * fabsf(area2);   // area rotation-invariant

    // z overlap + volumes
    const float zmax1 = bz + 0.5f * l1, zmin1 = bz - 0.5f * l1;
    const float zmax2 = gz + 0.5f * l2, zmin2 = gz - 0.5f * l2;
    const float zov = fmaxf(fminf(zmax1, zmax2) - fmaxf(zmin1, zmin2), 0.0f);
    const float inter3d = inter2d * zov;
    const float vol1 = w1 * h1 * l1, vol2 = w2 * h2 * l2;
    const float uni = vol1 + vol2 - inter3d;
    const float iou = inter3d * RCPF(uni);
    const float target = iou * 2.0f - 1.0f;

    // diou extras (world corners 0/2 recomputed, verified v7)
    const float ddx = bx - gx, ddy = by - gy, ddz = bz - gz;
    const float interdiag = ddx * ddx + ddy * ddy + ddz * ddz;
    const float v1x = hw1 * cs1 - hh1 * sn1, v1y = hw1 * sn1 + hh1 * cs1;
    const float w2x = hw2 * cs2 - hh2 * sn2, w2y = hw2 * sn2 + hh2 * cs2;
    const float outerh = fmaxf(fmaxf(zmax1, zmax2) - fminf(zmin1, zmin2), 0.0f);
    const float omx = fmaxf(fmaxf(bx - v1x, gx - w2x) - fminf(bx + v1x, gx + w2x), 0.0f);
    const float omy = fmaxf(fmaxf(by - v1y, gy - w2y) - fminf(by + v1y, gy + w2y), 0.0f);
    const float outerdiag = omx * omx + omy * omy + outerh * outerh;
    float diou = iou - interdiag * RCPF(outerdiag);
    diou = fminf(fmaxf(diou, -1.0f), 1.0f);

    return (fabsf(e.pred - target) + (1.0f - diou)) * e.mf;
}

__global__ __launch_bounds__(256, 4) void iou3d_loss_kernel(
    const float* __restrict__ pred_iou,
    const float* __restrict__ pred_boxes,
    const float* __restrict__ gt_boxes,
    const int*   __restrict__ mask,
    float* __restrict__ sums,
    int M)
{
    // SoA slot-major: sX[elem][slot][thread]; 36864B -> 4 blocks/CU
    __shared__ float sXs[2][9][256];
    __shared__ float sYs[2][9][256];
    const int tid = threadIdx.x;
    float* X0 = &sXs[0][0][tid];
    float* Y0 = &sYs[0][0][tid];
    float* X1 = &sXs[1][0][tid];
    float* Y1 = &sYs[1][0][tid];

    const int idx0 = blockIdx.x * blockDim.x + tid;
    const int stride = gridDim.x * blockDim.x;
    const int idx1 = idx0 + stride;
    const int ml = M - 1;
    const int i0 = idx0 < M ? idx0 : ml;
    const int i1 = idx1 < M ? idx1 : ml;

    EIn e0, e1;
    load_elem(e0, pred_iou, pred_boxes, gt_boxes, mask, i0, idx0 < M);
    load_elem(e1, pred_iou, pred_boxes, gt_boxes, mask, i1, idx1 < M);
    float contrib = elem_body(e0, X0, Y0) + elem_body(e1, X1, Y1);
    float mfv = e0.mf + e1.mf;

    // block reduction: wave shuffle -> LDS -> one atomic pair per block
    #pragma unroll
    for (int off = 32; off > 0; off >>= 1) {
        contrib += __shfl_down(contrib, off, 64);
        mfv     += __shfl_down(mfv, off, 64);
    }
    __shared__ float sC[4], sM[4];
    const int lane = tid & 63;
    const int wv = tid >> 6;
    if (lane == 0) { sC[wv] = contrib; sM[wv] = mfv; }
    __syncthreads();
    if (tid == 0) {
        float tc = sC[0] + sC[1] + sC[2] + sC[3];
        float tm = sM[0] + sM[1] + sM[2] + sM[3];
        atomicAdd(&sums[0], tc);
        atomicAdd(&sums[1], tm);
    }
}

__global__ void finalize_kernel(const float* __restrict__ sums, float* __restrict__ out) {
    if (threadIdx.x == 0 && blockIdx.x == 0)
        out[0] = sums[0] / fmaxf(sums[1], 1e-4f);
}

extern "C" void kernel_launch(void* const* d_in, const int* in_sizes, int n_in,
                              void* d_out, int out_size, void* d_ws, size_t ws_size,
                              hipStream_t stream) {
    const float* pred_iou   = (const float*)d_in[0];
    const float* pred_boxes = (const float*)d_in[1];
    const float* gt_boxes   = (const float*)d_in[2];
    const int*   mask       = (const int*)d_in[3];
    float* out  = (float*)d_out;
    float* sums = (float*)d_ws;
    const int M = in_sizes[0];

    hipMemsetAsync(sums, 0, 2 * sizeof(float), stream);
    const int block = 256;
    const int elems_per_thread = 2;
    int grid = (M + block * elems_per_thread - 1) / (block * elems_per_thread);
    if (grid < 1) grid = 1;
    hipLaunchKernelGGL(iou3d_loss_kernel, dim3(grid), dim3(block), 0, stream,
                       pred_iou, pred_boxes, gt_boxes, mask, sums, M);
    hipLaunchKernelGGL(finalize_kernel, dim3(1), dim3(64), 0, stream, sums, out);
}

// Round 9
// 96.279 us; speedup vs baseline: 1.2297x; 1.1628x over previous
//
#include <hip/hip_runtime.h>

// IoU3DLoss v9: kernel = v6 exactly (fastest measured, bit-exact: world-frame
// high-ILP geometry, SoA slot-major LDS rank-scatter, packed-key Batcher-8
// sort + LDS gather, 2 elems/thread, 4 blocks/CU).
// Reduction reworked: per-block partial sums written unconditionally to
// distinct d_ws slots (no atomics -> no zero-init -> memset launch removed);
// finalize reduces the 1024 partials in one block. 2 launches total.

#define RCPF(x) __builtin_amdgcn_rcpf(x)

__device__ __forceinline__ unsigned sortKeyU(float f) {
    unsigned u = __float_as_uint(f);
    return (u & 0x80000000u) ? ~u : (u | 0x80000000u);   // monotone float->uint
}

// Batcher odd-even merge sort, 8 keys, 19 comparators (validated v6/v7)
__device__ __forceinline__ void sort8(unsigned k[8]) {
#define CE(a, b) { unsigned lo = min(k[a], k[b]); unsigned hi = max(k[a], k[b]); k[a] = lo; k[b] = hi; }
    CE(0,1) CE(2,3) CE(4,5) CE(6,7)
    CE(0,2) CE(1,3) CE(4,6) CE(5,7)
    CE(1,2) CE(5,6)
    CE(0,4) CE(1,5) CE(2,6) CE(3,7)
    CE(2,4) CE(3,5)
    CE(1,2) CE(3,4) CE(5,6)
#undef CE
}

struct EIn {
    float b[7];   // pred box: x,y,z,w,h,l,alpha
    float g[8];   // gt box:   x,y,z,w,h,l,sin,cos
    float pred;
    float mf;
};

__device__ __forceinline__ void load_elem(EIn& e,
    const float* __restrict__ pred_iou, const float* __restrict__ pred_boxes,
    const float* __restrict__ gt_boxes, const int* __restrict__ mask,
    int gid, bool active)
{
    const float* pb = pred_boxes + (size_t)gid * 7;
    #pragma unroll
    for (int k = 0; k < 7; ++k) e.b[k] = pb[k];
    const float4 g0 = reinterpret_cast<const float4*>(gt_boxes)[(size_t)gid * 2 + 0];
    const float4 g1 = reinterpret_cast<const float4*>(gt_boxes)[(size_t)gid * 2 + 1];
    e.g[0] = g0.x; e.g[1] = g0.y; e.g[2] = g0.z; e.g[3] = g0.w;
    e.g[4] = g1.x; e.g[5] = g1.y; e.g[6] = g1.z; e.g[7] = g1.w;
    e.pred = pred_iou[gid];
    e.mf = (active && mask[gid] != 0) ? 1.0f : 0.0f;
}

// X, Y: this thread's LDS bases; slot j lives at X[j*256], Y[j*256].
__device__ __forceinline__ float elem_body(const EIn& e,
    float* __restrict__ X, float* __restrict__ Y)
{
    const float b1x = e.b[0], b1y = e.b[1], b1z = e.b[2];
    const float b1w = e.b[3], b1h = e.b[4], b1l = e.b[5], a1 = e.b[6];
    const float b2x = e.g[0], b2y = e.g[1], b2z = e.g[2];
    const float b2w = e.g[3], b2h = e.g[4], b2l = e.g[5];
    const float gsn = e.g[6], gcs = e.g[7];

    float sn1, cs1;
    __sincosf(a1, &sn1, &cs1);
    const float rn = __builtin_amdgcn_rsqf(gsn * gsn + gcs * gcs);
    const float sn2 = gsn * rn, cs2 = gcs * rn;

    const float xs[4] = {0.5f, -0.5f, -0.5f, 0.5f};
    const float ys[4] = {0.5f, 0.5f, -0.5f, -0.5f};
    float c1x[4], c1y[4], c2x[4], c2y[4];
    #pragma unroll
    for (int k = 0; k < 4; ++k) {
        float xx = xs[k] * b1w, yy = ys[k] * b1h;
        c1x[k] = xx * cs1 - yy * sn1 + b1x;
        c1y[k] = xx * sn1 + yy * cs1 + b1y;
        float x2 = xs[k] * b2w, y2 = ys[k] * b2h;
        c2x[k] = x2 * cs2 - y2 * sn2 + b2x;
        c2y[k] = x2 * sn2 + y2 * cs2 + b2y;
    }

    // ---- streaming rank-scatter into LDS slots (bit-verified semantics) ----
    unsigned r = 0u;
    const float eps = 1e-6f;

    {   // candidates 0-3: c1 corners inside box2 (multiplied-through tests)
        float ax = c2x[0], ay = c2y[0];
        float abx = c2x[1] - ax, aby = c2y[1] - ay;
        float adx = c2x[3] - ax, ady = c2y[3] - ay;
        float ab2 = abx * abx + aby * aby;
        float ad2 = adx * adx + ady * ady;
        float lo_ab = -eps * ab2, hi_ab = (1.0f + eps) * ab2;
        float lo_ad = -eps * ad2, hi_ad = (1.0f + eps) * ad2;
        #pragma unroll
        for (int k = 0; k < 4; ++k) {
            float apx = c1x[k] - ax, apy = c1y[k] - ay;
            float dab = apx * abx + apy * aby;
            float dad = apx * adx + apy * ady;
            bool ok = (dab > lo_ab) && (dab < hi_ab) && (dad > lo_ad) && (dad < hi_ad);
            unsigned rm = r < 8u ? r : 8u;
            X[rm * 256] = c1x[k];
            Y[rm * 256] = c1y[k];
            r += ok ? 1u : 0u;
        }
    }
    {   // candidates 4-7: c2 corners inside box1
        float ax = c1x[0], ay = c1y[0];
        float abx = c1x[1] - ax, aby = c1y[1] - ay;
        float adx = c1x[3] - ax, ady = c1y[3] - ay;
        float ab2 = abx * abx + aby * aby;
        float ad2 = adx * adx + ady * ady;
        float lo_ab = -eps * ab2, hi_ab = (1.0f + eps) * ab2;
        float lo_ad = -eps * ad2, hi_ad = (1.0f + eps) * ad2;
        #pragma unroll
        for (int k = 0; k < 4; ++k) {
            float apx = c2x[k] - ax, apy = c2y[k] - ay;
            float dab = apx * abx + apy * aby;
            float dad = apx * adx + apy * ady;
            bool ok = (dab > lo_ab) && (dab < hi_ab) && (dad > lo_ad) && (dad < hi_ad);
            unsigned rm = r < 8u ? r : 8u;
            X[rm * 256] = c2x[k];
            Y[rm * 256] = c2y[k];
            r += ok ? 1u : 0u;
        }
    }
    // candidates 8-23: edge crossings (reference's phantom t/u semantics)
    float e1dx[4], e1dy[4], e2dx[4], e2dy[4];
    #pragma unroll
    for (int l = 0; l < 4; ++l) {
        e1dx[l] = c1x[l] - c1x[(l + 1) & 3];   // x1 - x2
        e1dy[l] = c1y[l] - c1y[(l + 1) & 3];
        e2dx[l] = c2x[l] - c2x[(l + 1) & 3];   // x3 - x4
        e2dy[l] = c2y[l] - c2y[(l + 1) & 3];
    }
    #pragma unroll
    for (int l = 0; l < 4; ++l) {
        float x1 = c1x[l], y1 = c1y[l];
        #pragma unroll
        for (int m = 0; m < 4; ++m) {
            float rx = x1 - c2x[m], ry = y1 - c2y[m];
            float den  = e1dx[l] * e2dy[m] - e2dx[m] * e1dy[l];
            float numt = e2dx[m] * ry - e2dy[m] * rx;
            float numu = e1dx[l] * ry - e1dy[l] * rx;
            // t=numt/den in (0,1) <=> numt*den>0 && |numt|<|den|; same for u;
            // den==0 -> products 0 -> rejected (matches reference)
            float aden = fabsf(den);
            bool ok = (numt * den > 0.0f) && (fabsf(numt) < aden) &&
                      (numu * den > 0.0f) && (fabsf(numu) < aden);
            float t = numt * RCPF(den);
            float Xc = x1 - t * e1dx[l];
            float Yc = y1 - t * e1dy[l];
            unsigned rm = r < 8u ? r : 8u;
            X[rm * 256] = Xc;
            Y[rm * 256] = Yc;
            r += ok ? 1u : 0u;
        }
    }

    // ---- static readback of compacted slots ----
    float px[8], py[8];
    #pragma unroll
    for (int j = 0; j < 8; ++j) {
        px[j] = X[j * 256];
        py[j] = Y[j * 256];
    }
    int kcnt = (int)(r < 8u ? r : 8u);

    // centroid over valid slots (select, not multiply: garbage slots)
    float sxm = 0.0f, sym = 0.0f;
    #pragma unroll
    for (int j = 0; j < 8; ++j) {
        bool a = (j < kcnt);
        sxm += a ? px[j] : 0.0f;
        sym += a ? py[j] : 0.0f;
    }
    float rnv = RCPF(fmaxf((float)kcnt, 1.0f));
    float mx = sxm * rnv, my = sym * rnv;

    // packed keys: monotone-uint pseudo-angle, low 3 bits = slot index
    unsigned key[8];
    #pragma unroll
    for (int j = 0; j < 8; ++j) {
        float dx = px[j] - mx, dy = py[j] - my;
        float ad = fabsf(dx) + fabsf(dy);
        float rr = dx * RCPF(fmaxf(ad, 1e-30f));
        float k = __builtin_copysignf(1.0f - rr, dy);   // diamond pseudo-angle
        float kf = (j < kcnt) ? k : 1e9f;
        key[j] = (sortKeyU(kf) & 0xFFFFFFF8u) | (unsigned)j;
    }
    sort8(key);

    // gather sorted coordinates from LDS by packed index (bank = lane, free)
    float sx[8], sy[8];
    #pragma unroll
    for (int j = 0; j < 8; ++j) {
        unsigned idx = key[j] & 7u;
        sx[j] = X[idx * 256];
        sy[j] = Y[idx * 256];
    }

    // shoelace over first kcnt sorted vertices (== reference's cyclic form)
    float x0 = sx[0], y0 = sy[0];
    float area2 = 0.0f;
    #pragma unroll
    for (int v = 0; v < 8; ++v) {
        bool act = (v < kcnt);
        bool wrap = (v + 1 == kcnt);
        float nx2 = (v == 7) ? x0 : (wrap ? x0 : sx[v + 1]);
        float ny2 = (v == 7) ? y0 : (wrap ? y0 : sy[v + 1]);
        float term = sx[v] * ny2 - nx2 * sy[v];
        area2 += act ? term : 0.0f;
    }
    float inter2d = 0.5f * fabsf(area2);

    // z overlap + volumes
    float zmax1 = b1z + 0.5f * b1l, zmin1 = b1z - 0.5f * b1l;
    float zmax2 = b2z + 0.5f * b2l, zmin2 = b2z - 0.5f * b2l;
    float zov = fmaxf(fminf(zmax1, zmax2) - fmaxf(zmin1, zmin2), 0.0f);
    float inter3d = inter2d * zov;
    float vol1 = b1w * b1h * b1l;
    float vol2 = b2w * b2h * b2l;
    float uni = vol1 + vol2 - inter3d;
    float iou = inter3d * RCPF(uni);
    float target = iou * 2.0f - 1.0f;

    // diou extras
    float ddx = b1x - b2x, ddy = b1y - b2y, ddz = b1z - b2z;
    float interdiag = ddx * ddx + ddy * ddy + ddz * ddz;
    float outerh = fmaxf(fmaxf(zmax1, zmax2) - fminf(zmin1, zmin2), 0.0f);
    float omx = fmaxf(fmaxf(c1x[2], c2x[2]) - fminf(c1x[0], c2x[0]), 0.0f);
    float omy = fmaxf(fmaxf(c1y[2], c2y[2]) - fminf(c1y[0], c2y[0]), 0.0f);
    float outerdiag = omx * omx + omy * omy + outerh * outerh;
    float diou = iou - interdiag * RCPF(outerdiag);
    diou = fminf(fmaxf(diou, -1.0f), 1.0f);

    return (fabsf(e.pred - target) + (1.0f - diou)) * e.mf;
}

__global__ __launch_bounds__(256, 4) void iou3d_loss_kernel(
    const float* __restrict__ pred_iou,
    const float* __restrict__ pred_boxes,
    const float* __restrict__ gt_boxes,
    const int*   __restrict__ mask,
    float2* __restrict__ partials,   // [gridDim.x] {contrib_sum, mask_count}
    int M)
{
    // SoA slot-major: sX[elem][slot][thread]; 36864B -> 4 blocks/CU
    __shared__ float sXs[2][9][256];
    __shared__ float sYs[2][9][256];
    const int tid = threadIdx.x;
    float* X0 = &sXs[0][0][tid];
    float* Y0 = &sYs[0][0][tid];
    float* X1 = &sXs[1][0][tid];
    float* Y1 = &sYs[1][0][tid];

    const int idx0 = blockIdx.x * blockDim.x + tid;
    const int stride = gridDim.x * blockDim.x;
    const int idx1 = idx0 + stride;
    const int ml = M - 1;
    const int i0 = idx0 < M ? idx0 : ml;
    const int i1 = idx1 < M ? idx1 : ml;

    // single straight-line path: OOB lanes process a clamped element, mf=0
    EIn e0, e1;
    load_elem(e0, pred_iou, pred_boxes, gt_boxes, mask, i0, idx0 < M);
    load_elem(e1, pred_iou, pred_boxes, gt_boxes, mask, i1, idx1 < M);
    float contrib = elem_body(e0, X0, Y0) + elem_body(e1, X1, Y1);
    float mfv = e0.mf + e1.mf;

    // block reduction: wave shuffle -> LDS -> ONE unconditional partial write
    // per block (no atomic, no zero-init of d_ws needed)
    #pragma unroll
    for (int off = 32; off > 0; off >>= 1) {
        contrib += __shfl_down(contrib, off, 64);
        mfv     += __shfl_down(mfv, off, 64);
    }
    __shared__ float sC[4], sM[4];
    const int lane = tid & 63;
    const int wv = tid >> 6;
    if (lane == 0) { sC[wv] = contrib; sM[wv] = mfv; }
    __syncthreads();
    if (tid == 0) {
        float tc = sC[0] + sC[1] + sC[2] + sC[3];
        float tm = sM[0] + sM[1] + sM[2] + sM[3];
        partials[blockIdx.x] = make_float2(tc, tm);
    }
}

__global__ __launch_bounds__(256) void finalize_kernel(
    const float2* __restrict__ partials, int nparts,
    float* __restrict__ out)
{
    const int tid = threadIdx.x;
    float c = 0.0f, m = 0.0f;
    for (int i = tid; i < nparts; i += 256) {
        float2 p = partials[i];
        c += p.x; m += p.y;
    }
    #pragma unroll
    for (int off = 32; off > 0; off >>= 1) {
        c += __shfl_down(c, off, 64);
        m += __shfl_down(m, off, 64);
    }
    __shared__ float sC[4], sM[4];
    const int lane = tid & 63;
    const int wv = tid >> 6;
    if (lane == 0) { sC[wv] = c; sM[wv] = m; }
    __syncthreads();
    if (tid == 0) {
        float tc = sC[0] + sC[1] + sC[2] + sC[3];
        float tm = sM[0] + sM[1] + sM[2] + sM[3];
        out[0] = tc / fmaxf(tm, 1e-4f);
    }
}

extern "C" void kernel_launch(void* const* d_in, const int* in_sizes, int n_in,
                              void* d_out, int out_size, void* d_ws, size_t ws_size,
                              hipStream_t stream) {
    const float* pred_iou   = (const float*)d_in[0];
    const float* pred_boxes = (const float*)d_in[1];
    const float* gt_boxes   = (const float*)d_in[2];
    const int*   mask       = (const int*)d_in[3];
    float* out  = (float*)d_out;
    float2* partials = (float2*)d_ws;
    const int M = in_sizes[0];

    const int block = 256;
    const int elems_per_thread = 2;
    int grid = (M + block * elems_per_thread - 1) / (block * elems_per_thread);
    if (grid < 1) grid = 1;
    hipLaunchKernelGGL(iou3d_loss_kernel, dim3(grid), dim3(block), 0, stream,
                       pred_iou, pred_boxes, gt_boxes, mask, partials, M);
    hipLaunchKernelGGL(finalize_kernel, dim3(1), dim3(block), 0, stream,
                       partials, grid, out);
}